// Round 1
// baseline (5449.162 us; speedup 1.0000x reference)
//
#include <hip/hip_runtime.h>
#include <cstdint>
#include <cstddef>

typedef unsigned int u32;
typedef unsigned short u16;
typedef __bf16 bf16;
typedef bf16 bf16x8 __attribute__((ext_vector_type(8)));
typedef u16 u16x8 __attribute__((ext_vector_type(8)));
typedef float f32x4 __attribute__((ext_vector_type(4)));

union V8 { bf16x8 b; u16x8 u; };

// ---- constants ----
#define T_STEPS 512
#define NTILE 65536              // 256*256 elements per [B,DL] slab
// d_out float offsets
#define OFF_H 0ULL
#define OFF_C 33619968ULL        // 513*65536
#define OFF_F 67239936ULL        // 2*513*65536
#define OFF_I 100794368ULL       // OFF_F + 512*65536
#define OFF_O 134348800ULL       // OFF_I + 512*65536
// workspace byte offsets
#define WHP_OFF   0ULL           // 512 KiB packed Wh (bf16, B-frag layout)
#define WXP_OFF   524288ULL      // 512 KiB packed Wx
#define HX_OFF    1048576ULL     // 256 KiB h exchange (16 pairs x 2 phases x 8KB)
#define FLAGS_OFF 1310720ULL     // 128 B flags
#define XG_OFF    2097152ULL     // 256 MiB Xg (bf16, acc-frag layout)
#define WS_NEED   (XG_OFF + 268435456ULL)

__device__ __forceinline__ u16 f2b(float f) {
  u32 u = __float_as_uint(f);
  u32 r = (u + 0x7FFFu + ((u >> 16) & 1u)) >> 16;   // RNE
  return (u16)r;
}
__device__ __forceinline__ float b2f(u16 s) { return __uint_as_float(((u32)s) << 16); }
__device__ __forceinline__ float sigm(float x) { return 1.0f / (1.0f + __expf(-x)); }
__device__ __forceinline__ float tanh_fast(float x) { return 1.0f - 2.0f / (__expf(2.0f * x) + 1.0f); }

// ---------------- Phase 0: pack weights into MFMA B-fragment layout ----------------
// B-frag (16x16x32 bf16): lane holds B[k = 32*kc + 8*(lane>>4) + jj][n = lane&15], jj=0..7
// layout: [slice s=j*8+w][gate g][kc][lane][jj]  (8 bf16 = 16B per lane)
__global__ void pack_weights(const float* __restrict__ Wf, const float* __restrict__ Wi,
                             const float* __restrict__ Wc, const float* __restrict__ Wo,
                             u16* __restrict__ Whp, u16* __restrict__ Wxp) {
  int idx = blockIdx.x * blockDim.x + threadIdx.x;     // 32768 threads
  int lane = idx & 63, kc = (idx >> 6) & 7, g = (idx >> 9) & 3, s = idx >> 11;
  const float* W = (g == 0) ? Wf : (g == 1) ? Wi : (g == 2) ? Wc : Wo;
  int hc = (s >> 3) * 128 + (s & 7) * 16 + (lane & 15);   // output column (h col)
  int kb = kc * 32 + (lane >> 4) * 8;
#pragma unroll
  for (int jj = 0; jj < 8; ++jj) {
    Whp[(size_t)idx * 8 + jj] = f2b(W[hc * 512 + kb + jj]);          // h part: cols [0,256)
    Wxp[(size_t)idx * 8 + jj] = f2b(W[hc * 512 + 256 + kb + jj]);    // x part: cols [256,512)
  }
}

// ---------------- Phase 1: Xg[t,b,n] = X@Wx^T + bias, acc-frag layout bf16 ----------------
// wave tile: 16 rows x (4 gates x 16 hcols); Xg slot ((t*16+bt)*16+s): 64 lanes x 32B
__launch_bounds__(512, 2)
__global__ void xpart_gemm(const float* __restrict__ X,
                           const float* __restrict__ bfv, const float* __restrict__ biv,
                           const float* __restrict__ bcv, const float* __restrict__ bov,
                           const u16* __restrict__ Wxp, u16* __restrict__ Xg) {
  const int j = blockIdx.y, mgrp = blockIdx.x;          // j in [0,2), mgrp in [0,128)
  const int w = threadIdx.x >> 6, lane = threadIdx.x & 63;
  const int s = j * 8 + w;
  V8 bfrag[4][8];
  const u16x8* wp = (const u16x8*)Wxp + (size_t)s * 32 * 64;
#pragma unroll
  for (int g = 0; g < 4; ++g)
#pragma unroll
    for (int kc = 0; kc < 8; ++kc)
      bfrag[g][kc].u = wp[(g * 8 + kc) * 64 + lane];
  const int hc = j * 128 + w * 16 + (lane & 15);
  float bias[4] = { bfv[hc], biv[hc], bcv[hc], bov[hc] };

  for (int it = 0; it < 64; ++it) {
    int mt = 8191 - (it * 128 + mgrp);                  // descending t: IF keeps t~0 hot for phase 2
    const float* xp = X + (size_t)(mt * 16 + (lane & 15)) * 256 + (lane >> 4) * 8;
    V8 af[8];
#pragma unroll
    for (int kc = 0; kc < 8; ++kc) {
      f32x4 x0 = *(const f32x4*)(xp + kc * 32);
      f32x4 x1 = *(const f32x4*)(xp + kc * 32 + 4);
#pragma unroll
      for (int e = 0; e < 4; ++e) { af[kc].u[e] = f2b(x0[e]); af[kc].u[4 + e] = f2b(x1[e]); }
    }
    f32x4 acc[4];
#pragma unroll
    for (int g = 0; g < 4; ++g) acc[g] = (f32x4){ bias[g], bias[g], bias[g], bias[g] };
#pragma unroll
    for (int kc = 0; kc < 8; ++kc)
#pragma unroll
      for (int g = 0; g < 4; ++g)
        acc[g] = __builtin_amdgcn_mfma_f32_16x16x32_bf16(af[kc].b, bfrag[g][kc].b, acc[g], 0, 0, 0);
    u16x8 o0, o1;
#pragma unroll
    for (int r = 0; r < 4; ++r) {
      o0[r] = f2b(acc[0][r]); o0[4 + r] = f2b(acc[1][r]);
      o1[r] = f2b(acc[2][r]); o1[4 + r] = f2b(acc[3][r]);
    }
    u16x8* op = (u16x8*)(Xg + ((size_t)mt * 16 + s) * 1024) + lane * 2;
    op[0] = o0; op[1] = o1;
  }
}

// ---------------- Phase 2: persistent recurrent kernel ----------------
// 32 blocks: pair i=batch-tile (16 rows), j=gate-col half. Wh half in registers.
// wave tile: 16 rows x 16 hcols x 4 gates. c-state in registers. h exchanged via ws.
__launch_bounds__(512, 2)
__global__ void lstm_recurrent(const u16* __restrict__ Whp, const u16* __restrict__ Xg,
                               u16* __restrict__ hx, u32* __restrict__ flags,
                               float* __restrict__ out) {
  const int l = blockIdx.x;
  const int j = (l >> 3) & 1;                 // pair halves are (l, l+8): same XCD heuristic
  const int i = (l & 7) | ((l >> 4) << 3);
  const int w = threadIdx.x >> 6, lane = threadIdx.x & 63;
  const int s = j * 8 + w;

  V8 bfrag[4][8];
  const u16x8* wp = (const u16x8*)Whp + (size_t)s * 32 * 64;
#pragma unroll
  for (int g = 0; g < 4; ++g)
#pragma unroll
    for (int kc = 0; kc < 8; ++kc)
      bfrag[g][kc].u = wp[(g * 8 + kc) * 64 + lane];

  f32x4 cst = (f32x4){0.f, 0.f, 0.f, 0.f};
  u32* pflag = flags + i * 2 + (1 - j);
  u32* myflag = flags + i * 2 + j;
  u16* hxi = hx + (size_t)i * 8192;           // 2 phases x 4096 u16

  const int bloc = (lane >> 4) * 4;           // local row base (quad*4)
  const int hc = j * 128 + w * 16 + (lane & 15);
  const int kc2 = hc >> 5, q2 = (hc >> 3) & 3, j2 = hc & 7;   // A-frag scatter coords
  const size_t eobase = (size_t)(i * 16 + bloc) * 256 + hc;

  for (int t = 0; t < T_STEPS; ++t) {
    // acc init from Xg (x-part + bias), independent of recurrence
    const u16x8* xgp = (const u16x8*)(Xg + ((size_t)(t * 16 + i) * 16 + s) * 1024) + lane * 2;
    u16x8 x0 = xgp[0], x1 = xgp[1];
    f32x4 acc[4];
#pragma unroll
    for (int r = 0; r < 4; ++r) {
      acc[0][r] = b2f(x0[r]); acc[1][r] = b2f(x0[4 + r]);
      acc[2][r] = b2f(x1[r]); acc[3][r] = b2f(x1[4 + r]);
    }
    if (t > 0) {
      while (__hip_atomic_load(pflag, __ATOMIC_RELAXED, __HIP_MEMORY_SCOPE_AGENT) < (u32)t) {}
      __threadfence();                         // acquire: partner h visible
      const u16x8* ap = (const u16x8*)(hxi + (size_t)(t & 1) * 4096);
      V8 af[8];
#pragma unroll
      for (int kc = 0; kc < 8; ++kc) af[kc].u = ap[kc * 64 + lane];
#pragma unroll
      for (int kc = 0; kc < 8; ++kc)
#pragma unroll
        for (int g = 0; g < 4; ++g)
          acc[g] = __builtin_amdgcn_mfma_f32_16x16x32_bf16(af[kc].b, bfrag[g][kc].b, acc[g], 0, 0, 0);
    }
    // elementwise gates
    f32x4 fv, iv, gv, ov, hv;
#pragma unroll
    for (int r = 0; r < 4; ++r) {
      fv[r] = sigm(acc[0][r]);
      iv[r] = sigm(acc[1][r]);
      gv[r] = tanh_fast(acc[2][r]);
      ov[r] = sigm(acc[3][r]);
      cst[r] = fv[r] * cst[r] + iv[r] * gv[r];
      hv[r] = ov[r] * tanh_fast(cst[r]);
    }
    // fp32 outputs
    size_t o1 = (size_t)(t + 1) * NTILE + eobase;
    size_t o2 = (size_t)t * NTILE + eobase;
#pragma unroll
    for (int r = 0; r < 4; ++r) {
      out[OFF_H + o1 + r * 256] = hv[r];
      out[OFF_C + o1 + r * 256] = cst[r];
      out[OFF_F + o2 + r * 256] = fv[r];
      out[OFF_I + o2 + r * 256] = iv[r];
      out[OFF_O + o2 + r * 256] = ov[r];
    }
    if (t < T_STEPS - 1) {
      // publish h (pre-swizzled into A-frag layout): 4 scattered 2B stores
      u16* hb = hxi + (size_t)((t + 1) & 1) * 4096;
#pragma unroll
      for (int r = 0; r < 4; ++r)
        hb[(kc2 * 64 + q2 * 16 + bloc + r) * 8 + j2] = f2b(hv[r]);
      __syncthreads();
      if (threadIdx.x == 0) {
        __threadfence();                       // release: h stores drained to agent scope
        __hip_atomic_store(myflag, (u32)(t + 1), __ATOMIC_RELEASE, __HIP_MEMORY_SCOPE_AGENT);
      }
    }
  }
}

extern "C" void kernel_launch(void* const* d_in, const int* in_sizes, int n_in,
                              void* d_out, int out_size, void* d_ws, size_t ws_size,
                              hipStream_t stream) {
  if (ws_size < WS_NEED) return;   // workspace probe: fail cleanly if ws too small

  const float* X   = (const float*)d_in[0];
  const float* Wf  = (const float*)d_in[1];
  const float* bfv = (const float*)d_in[2];
  const float* Wi  = (const float*)d_in[3];
  const float* biv = (const float*)d_in[4];
  const float* Wc  = (const float*)d_in[5];
  const float* bcv = (const float*)d_in[6];
  const float* Wo  = (const float*)d_in[7];
  const float* bov = (const float*)d_in[8];
  float* out = (float*)d_out;

  char* ws = (char*)d_ws;
  u16* Whp  = (u16*)(ws + WHP_OFF);
  u16* Wxp  = (u16*)(ws + WXP_OFF);
  u16* hx   = (u16*)(ws + HX_OFF);
  u32* flags = (u32*)(ws + FLAGS_OFF);
  u16* Xg   = (u16*)(ws + XG_OFF);

  hipMemsetAsync(flags, 0, 128, stream);
  hipMemsetAsync(out, 0, (size_t)NTILE * 4, stream);                         // H[0] = 0
  hipMemsetAsync(out + OFF_C, 0, (size_t)NTILE * 4, stream);                 // C[0] = 0

  pack_weights<<<128, 256, 0, stream>>>(Wf, Wi, Wc, Wo, Whp, Wxp);
  xpart_gemm<<<dim3(128, 2), 512, 0, stream>>>(X, bfv, biv, bcv, bov, Wxp, Xg);
  lstm_recurrent<<<32, 512, 0, stream>>>(Whp, Xg, hx, flags, out);
}